// Round 8
// baseline (5051.157 us; speedup 1.0000x reference)
//
#include <hip/hip_runtime.h>
#include <math.h>

#define EPSF     0.1f
#define BB       8
#define NN       2048
#define DIM      32
#define MAX_ITER 100
#define THRESHF  0.1f
// base-2 domain constants: exp(x) = exp2(x*log2e)
#define C20L2E 28.853900817779268f   // (2/EPS)*log2e
#define C10L2E 14.426950408889634f   // (1/EPS)*log2e
#define LN2F   0.6931471805599453f

typedef __attribute__((ext_vector_type(8))) short  sh8;    // 8 x bf16 (4 VGPRs)
typedef __attribute__((ext_vector_type(4))) float  f32x4;  // MFMA C/D

__device__ __forceinline__ float ex2(float x) { return __builtin_amdgcn_exp2f(x); }
__device__ __forceinline__ float lg2(float x) { return __builtin_amdgcn_logf(x); }

// coherent (agent-scope, cache-bypassing) scalar access to cross-block data
__device__ __forceinline__ float coh_load(const float* p) {
  return __uint_as_float(__hip_atomic_load((const unsigned*)p, __ATOMIC_RELAXED,
                                           __HIP_MEMORY_SCOPE_AGENT));
}
__device__ __forceinline__ void coh_store(float* p, float v) {
  __hip_atomic_store((unsigned*)p, __float_as_uint(v), __ATOMIC_RELAXED,
                     __HIP_MEMORY_SCOPE_AGENT);
}

__device__ __forceinline__ unsigned short bf16_rne(float v) {
  unsigned u = __float_as_uint(v);
  unsigned r = (u + 0x7FFFu + ((u >> 16) & 1u)) >> 16;
  return (unsigned short)r;
}

// Split fp32 -> bf16 hi/lo, compute row |.|^2 and initial w2 = 10*log2e*(0 - |.|^2).
__global__ __launch_bounds__(256) void prep_kernel(const float* __restrict__ in,
                                                   unsigned short* __restrict__ hi,
                                                   unsigned short* __restrict__ lo,
                                                   float* __restrict__ snorm,
                                                   float* __restrict__ w2init) {
  const int tid = blockIdx.x * 256 + threadIdx.x;
  const int row = tid >> 5, k = tid & 31;
  float val = in[tid];
  unsigned short h = bf16_rne(val);
  float hf = __uint_as_float(((unsigned)h) << 16);
  unsigned short l = bf16_rne(val - hf);
  hi[tid] = h;
  lo[tid] = l;
  float sq = val * val;
#pragma unroll
  for (int off = 1; off < 32; off <<= 1) sq += __shfl_xor(sq, off, 64);
  if (k == 0) {
    snorm[row] = sq;
    w2init[row] = -sq * C10L2E;
  }
  (void)k;
}

// Per-batch barrier: 64 blocks share one monotonic counter (never reset; the
// target scales with barrier number -> no reset races). Cross-block data
// travels only via coherent atomics, so arrival needs just vmcnt(0) + relaxed
// RMW; the wait spins on relaxed loads (no cache invalidates anywhere).
__device__ __forceinline__ void batch_barrier(int* __restrict__ cnt, int target) {
  __syncthreads();
  if (threadIdx.x == 0) {
    asm volatile("s_waitcnt vmcnt(0)" ::: "memory");
    __hip_atomic_fetch_add(cnt, 1, __ATOMIC_RELAXED, __HIP_MEMORY_SCOPE_AGENT);
    while (__hip_atomic_load(cnt, __ATOMIC_RELAXED, __HIP_MEMORY_SCOPE_AGENT) < target) {
      __builtin_amdgcn_s_sleep(1);
    }
  }
  __syncthreads();
}

// One half-sweep for this block's 32 rows, 512 threads = 8 waves.
// Wave w owns j-eighth w (256 cols), computes BOTH row-groups per B-chunk
// (every B byte loaded once per block per phase). The opposite-dual values are
// prefetched into 16 REGISTERS per lane via coherent loads at phase start --
// no LDS staging, no staging __syncthreads, no LDS reads in the inner loop
// (R7's 2.7e7 bank conflicts eliminated). tj loop fully unrolled so wreg[tj]
// is compile-time-indexed (no scratch). 8-way LSE merge in LDS (fixed order).
template <bool REC>
__device__ __forceinline__ void sweep_phase(
    const sh8 a0h, const sh8 a0l, const sh8 a1h, const sh8 a1l,
    const unsigned short* __restrict__ Bh, const unsigned short* __restrict__ Bl,
    float* __restrict__ wself2, const float* __restrict__ woth2,
    float* __restrict__ errSlot,
    const int b, const int i0, const float cst, const float sav, float& uold,
    float lm[32][8], float ls[32][8]) {
  const int w    = threadIdx.x >> 6;   // j-eighth
  const int lane = threadIdx.x & 63;
  const int l15  = lane & 15, q = lane >> 4;
  const int jbase = w * 256;

  // register prefetch of the 16 opposite-dual values this lane needs
  // (coherent: written by sibling blocks; 16 independent MALL loads in flight)
  float wreg[16];
#pragma unroll
  for (int tj = 0; tj < 16; tj++)
    wreg[tj] = coh_load(&woth2[b * NN + jbase + tj * 16 + l15]);

  float m2[8], ss[8];
#pragma unroll
  for (int r = 0; r < 8; r++) { m2[r] = -1e30f; ss[r] = 0.f; }

#pragma unroll
  for (int tj = 0; tj < 16; tj++) {
    const int j = jbase + tj * 16;
    const size_t brow = ((size_t)(b * NN + j + l15)) * DIM + q * 8;
    const sh8 bh = *(const sh8*)(Bh + brow);
    const sh8 bl = *(const sh8*)(Bl + brow);
    f32x4 acc0 = {0.f, 0.f, 0.f, 0.f};
    f32x4 acc1 = {0.f, 0.f, 0.f, 0.f};
    acc0 = __builtin_amdgcn_mfma_f32_16x16x32_bf16(a0h, bh, acc0, 0, 0, 0);
    acc1 = __builtin_amdgcn_mfma_f32_16x16x32_bf16(a1h, bh, acc1, 0, 0, 0);
    acc0 = __builtin_amdgcn_mfma_f32_16x16x32_bf16(a0h, bl, acc0, 0, 0, 0);
    acc1 = __builtin_amdgcn_mfma_f32_16x16x32_bf16(a1h, bl, acc1, 0, 0, 0);
    acc0 = __builtin_amdgcn_mfma_f32_16x16x32_bf16(a0l, bh, acc0, 0, 0, 0);
    acc1 = __builtin_amdgcn_mfma_f32_16x16x32_bf16(a1l, bh, acc1, 0, 0, 0);
    const float wj = wreg[tj];
#pragma unroll
    for (int r = 0; r < 8; r++) {
      const float S = (r < 4) ? acc0[r & 3] : acc1[r & 3];
      const float t = fmaf(S, C20L2E, wj);
      const float d = t - m2[r];
      const float e = ex2(-fabsf(d));           // single transcendental
      const bool up = d > 0.f;
      ss[r] = up ? fmaf(ss[r], e, 1.f) : (ss[r] + e);
      m2[r] = fmaxf(m2[r], t);
    }
  }

  // reduce (m,s) across the 16 lanes that share a row-set
#pragma unroll
  for (int off = 1; off < 16; off <<= 1) {
#pragma unroll
    for (int r = 0; r < 8; r++) {
      const float mo = __shfl_xor(m2[r], off, 64);
      const float so = __shfl_xor(ss[r], off, 64);
      const float mn = fmaxf(m2[r], mo);
      ss[r] = ss[r] * ex2(m2[r] - mn) + so * ex2(mo - mn);
      m2[r] = mn;
    }
  }

  if (l15 == 0) {
#pragma unroll
    for (int r = 0; r < 4; r++) {
      lm[q * 4 + r][w] = m2[r];          ls[q * 4 + r][w] = ss[r];
      lm[16 + q * 4 + r][w] = m2[4 + r]; ls[16 + q * 4 + r][w] = ss[4 + r];
    }
  }
  __syncthreads();
  if (threadIdx.x < 32) {
    const int row = threadIdx.x;
    float m = lm[row][0], s = ls[row][0];
#pragma unroll
    for (int p = 1; p < 8; p++) {
      const float mo = lm[row][p], so = ls[row][p];
      const float mn = fmaxf(m, mo);
      s = s * ex2(m - mn) + so * ex2(mo - mn);
      m = mn;
    }
    const float lse = (m + lg2(s)) * LN2F;   // natural-log LSE
    const int gi = b * NN + i0 + row;
    const float nu = cst + sav - EPSF * lse;
    coh_store(&wself2[gi], (nu - sav) * C10L2E);
    if (REC) {
      float du = fabsf(nu - uold);
#pragma unroll
      for (int off = 1; off < 32; off <<= 1) du += __shfl_xor(du, off, 64);
      if (threadIdx.x == 0) atomicAdd(errSlot, du);   // device-scope, no reader in loop
      uold = nu;
    }
  }
  __syncthreads();
}

// Persistent kernel: full Sinkhorn loop, one dispatch. 512 WGs x 512 thr
// (2 blocks/CU, 16 waves/CU). b = blk&7 pins each batch to one XCD (512 KB
// read-only panels, L2-resident); barriers are per-batch (64 blocks).
// PASS1: run all MAX_ITER iterations, record err(t,b). PASS2 (rerun for exact
// freeze semantics): run *nIterDev iterations (0 => immediate exit); barrier
// counters continue monotonically from pass 1's 2*MAX_ITER barriers.
template <bool PASS1>
__global__ __launch_bounds__(512, 4) void solve_kernel(
    const unsigned short* __restrict__ xh, const unsigned short* __restrict__ xl,
    const unsigned short* __restrict__ yh, const unsigned short* __restrict__ yl,
    const float* __restrict__ sx, const float* __restrict__ sy,
    float* __restrict__ wu2, float* __restrict__ wv2,
    float* __restrict__ errTab, int* __restrict__ gcnt,
    const int* __restrict__ nIterDev,
    float emu, float enu) {
  __shared__ float lm[32][8];
  __shared__ float ls[32][8];
  const int b  = blockIdx.x & 7;
  const int i0 = (blockIdx.x >> 3) * 32;
  const int nIter = PASS1 ? MAX_ITER : *nIterDev;
  if (nIter == 0) return;   // pass 2 no-op when pass 1 state is already final

  const int lane = threadIdx.x & 63;
  const int l15 = lane & 15, q = lane >> 4;

  // hoisted loop-invariant A fragments, both row-groups, both phases
  const size_t arow0 = ((size_t)(b * NN + i0 + l15)) * DIM + q * 8;
  const sh8 xa0h = *(const sh8*)(xh + arow0);
  const sh8 xa0l = *(const sh8*)(xl + arow0);
  const sh8 xa1h = *(const sh8*)(xh + arow0 + 16 * DIM);
  const sh8 xa1l = *(const sh8*)(xl + arow0 + 16 * DIM);
  const sh8 ya0h = *(const sh8*)(yh + arow0);
  const sh8 ya0l = *(const sh8*)(yl + arow0);
  const sh8 ya1h = *(const sh8*)(yh + arow0 + 16 * DIM);
  const sh8 ya1l = *(const sh8*)(yl + arow0 + 16 * DIM);

  // per-row constants & previous-u held in registers of the 32 writer threads
  float savx = 0.f, savy = 0.f, uold = 0.f, dummy = 0.f;
  if (threadIdx.x < 32) {
    savx = sx[b * NN + i0 + threadIdx.x];
    savy = sy[b * NN + i0 + threadIdx.x];
  }

  int* cnt = &gcnt[b * 32];
  int tgt = (PASS1 ? 0 : 2 * MAX_ITER) * 64;

  for (int it = 0; it < nIter; ++it) {
    // u-phase: x rows vs all y, weights wv2 -> writes wu2 (+ err in pass 1)
    sweep_phase<PASS1>(xa0h, xa0l, xa1h, xa1l, yh, yl, wu2, wv2,
                       PASS1 ? &errTab[it * BB + b] : wu2,
                       b, i0, emu, savx, uold, lm, ls);
    tgt += 64;
    batch_barrier(cnt, tgt);
    // v-phase: y rows vs all x, weights (updated) wu2 -> writes wv2
    sweep_phase<false>(ya0h, ya0l, ya1h, ya1l, xh, xl, wv2, wu2, wu2,
                       b, i0, enu, savy, dummy, lm, ls);
    tgt += 64;
    batch_barrier(cnt, tgt);
  }
}

// Find T* = first iteration with mean-batch err < THRESH. If T* < MAX_ITER-1,
// the reference would have frozen at state(T*): reset duals and request a
// rerun of T*+1 iterations (never taken for inputs that don't converge early).
__global__ __launch_bounds__(256) void tstar_kernel(const float* __restrict__ errTab,
                                                    int* __restrict__ nIterDev,
                                                    const float* __restrict__ sx,
                                                    const float* __restrict__ sy,
                                                    float* __restrict__ wu2,
                                                    float* __restrict__ wv2) {
  __shared__ int best;
  if (threadIdx.x == 0) best = MAX_ITER;
  __syncthreads();
  if (threadIdx.x < MAX_ITER) {
    float e = 0.f;
#pragma unroll
    for (int bb = 0; bb < BB; bb++) e += errTab[threadIdx.x * BB + bb];
    if (e * 0.125f < THRESHF) atomicMin(&best, (int)threadIdx.x);
  }
  __syncthreads();
  const int T = best;
  const int n2 = (T < MAX_ITER - 1) ? T + 1 : 0;
  if (threadIdx.x == 0) *nIterDev = n2;
  if (n2 > 0) {   // reset duals to iteration-0 state for the rerun
    for (int idx = threadIdx.x; idx < BB * NN; idx += 256) {
      wu2[idx] = -sx[idx] * C10L2E;
      wv2[idx] = -sy[idx] * C10L2E;
    }
  }
}

// C = sx_i + sy_j - 2S ; pi = exp2(wu2_i + wv2_j + 20log2e*S) ; cost[b] += pi*C
__global__ __launch_bounds__(256) void finalize_kernel(const unsigned short* __restrict__ xh,
                                                       const unsigned short* __restrict__ xl,
                                                       const unsigned short* __restrict__ yh,
                                                       const unsigned short* __restrict__ yl,
                                                       const float* __restrict__ sx,
                                                       const float* __restrict__ sy,
                                                       const float* __restrict__ wu2,
                                                       const float* __restrict__ wv2,
                                                       float* __restrict__ C,
                                                       float* __restrict__ pi,
                                                       float* __restrict__ cost) {
  const int b  = blockIdx.z;
  const int wv = threadIdx.x >> 6;
  const int lane = threadIdx.x & 63;
  const int l15 = lane & 15, q = lane >> 4;
  const int i0 = blockIdx.y * 128 + wv * 32;
  const int j0 = blockIdx.x * 256;

  const size_t arow0 = ((size_t)(b * NN + i0 + l15)) * DIM + q * 8;
  const sh8 a0h = *(const sh8*)(xh + arow0);
  const sh8 a0l = *(const sh8*)(xl + arow0);
  const sh8 a1h = *(const sh8*)(xh + arow0 + 16 * DIM);
  const sh8 a1l = *(const sh8*)(xl + arow0 + 16 * DIM);

  float sx0[8], wu0[8];
#pragma unroll
  for (int r = 0; r < 8; r++) {
    const int gi = b * NN + i0 + ((r < 4) ? (q * 4 + (r & 3)) : (16 + q * 4 + (r & 3)));
    sx0[r] = sx[gi];
    wu0[r] = wu2[gi];
  }

  float acc = 0.f;
#pragma unroll 2
  for (int tj = 0; tj < 16; tj++) {
    const int j = j0 + tj * 16;
    const size_t brow = ((size_t)(b * NN + j + l15)) * DIM + q * 8;
    const sh8 bh = *(const sh8*)(yh + brow);
    const sh8 bl = *(const sh8*)(yl + brow);
    f32x4 acc0 = {0.f, 0.f, 0.f, 0.f};
    f32x4 acc1 = {0.f, 0.f, 0.f, 0.f};
    acc0 = __builtin_amdgcn_mfma_f32_16x16x32_bf16(a0h, bh, acc0, 0, 0, 0);
    acc1 = __builtin_amdgcn_mfma_f32_16x16x32_bf16(a1h, bh, acc1, 0, 0, 0);
    acc0 = __builtin_amdgcn_mfma_f32_16x16x32_bf16(a0h, bl, acc0, 0, 0, 0);
    acc1 = __builtin_amdgcn_mfma_f32_16x16x32_bf16(a1h, bl, acc1, 0, 0, 0);
    acc0 = __builtin_amdgcn_mfma_f32_16x16x32_bf16(a0l, bh, acc0, 0, 0, 0);
    acc1 = __builtin_amdgcn_mfma_f32_16x16x32_bf16(a1l, bh, acc1, 0, 0, 0);
    const int gj = b * NN + j + l15;
    const float syj = sy[gj];
    const float wvj = wv2[gj];
#pragma unroll
    for (int r = 0; r < 8; r++) {
      const float S = (r < 4) ? acc0[r & 3] : acc1[r & 3];
      const int irow = i0 + ((r < 4) ? (q * 4 + (r & 3)) : (16 + q * 4 + (r & 3)));
      const float Cv = fmaf(-2.f, S, sx0[r] + syj);
      const float p  = ex2(fmaf(S, C20L2E, wu0[r] + wvj));
      const size_t addr = ((size_t)(b * NN + irow)) * NN + j + l15;
      C[addr]  = Cv;
      pi[addr] = p;
      acc = fmaf(p, Cv, acc);
    }
  }
#pragma unroll
  for (int off = 1; off < 64; off <<= 1) acc += __shfl_xor(acc, off, 64);
  __shared__ float red[4];
  if (lane == 0) red[wv] = acc;
  __syncthreads();
  if (threadIdx.x == 0) atomicAdd(&cost[b], red[0] + red[1] + red[2] + red[3]);
}

extern "C" void kernel_launch(void* const* d_in, const int* in_sizes, int n_in,
                              void* d_out, int out_size, void* d_ws, size_t ws_size,
                              hipStream_t stream) {
  const float* x = (const float*)d_in[0];
  const float* y = (const float*)d_in[1];
  float* out  = (float*)d_out;
  float* cost = out;                              // [8]
  float* pi   = out + 8;                          // [8,2048,2048]
  float* C    = out + 8 + (size_t)BB * NN * NN;   // [8,2048,2048]

  float* ws = (float*)d_ws;
  const int BN = BB * NN;                         // 16384
  float* wu2 = ws;                                // [16384]
  float* wv2 = ws + BN;
  float* sx  = ws + 2 * BN;
  float* sy  = ws + 3 * BN;
  float* errTab = ws + 4 * BN;                    // [100*8], zeroed
  int*   gcnt   = (int*)(ws + 4 * BN + 1024);     // 8 counters, stride 32 ints
  int*   nIterDev = (int*)(ws + 4 * BN + 1280);
  unsigned short* xh = (unsigned short*)(ws + 4 * BN + 1536);
  const size_t NE = (size_t)BB * NN * DIM;        // 524288
  unsigned short* xl = xh + NE;
  unsigned short* yh = xh + 2 * NE;
  unsigned short* yl = xh + 3 * NE;

  // zero errTab + barrier counters + nIter (prep rewrites wu2/wv2/sx/sy)
  hipMemsetAsync(errTab, 0, 1536 * sizeof(float), stream);
  hipMemsetAsync(d_out, 0, 8 * sizeof(float), stream);

  prep_kernel<<<2048, 256, 0, stream>>>(x, xh, xl, sx, wu2);
  prep_kernel<<<2048, 256, 0, stream>>>(y, yh, yl, sy, wv2);

  const float emu = (float)(0.1 * log(1.0 / 2048.0 + 1e-8));
  const float enu = emu;

  solve_kernel<true><<<512, 512, 0, stream>>>(xh, xl, yh, yl, sx, sy, wu2, wv2,
                                              errTab, gcnt, nIterDev, emu, enu);
  tstar_kernel<<<1, 256, 0, stream>>>(errTab, nIterDev, sx, sy, wu2, wv2);
  solve_kernel<false><<<512, 512, 0, stream>>>(xh, xl, yh, yl, sx, sy, wu2, wv2,
                                               errTab, gcnt, nIterDev, emu, enu);

  finalize_kernel<<<dim3(8, 16, BB), 256, 0, stream>>>(xh, xl, yh, yl, sx, sy,
                                                       wu2, wv2, C, pi, cost);
}

// Round 9
// 3623.746 us; speedup vs baseline: 1.3939x; 1.3939x over previous
//
#include <hip/hip_runtime.h>
#include <math.h>

#define EPSF     0.1f
#define BB       8
#define NN       2048
#define DIM      32
#define MAX_ITER 100
#define THRESHF  0.1f
#define SAFE_ITERS 6
// base-2 domain constants: exp(x) = exp2(x*log2e)
#define C20L2E 28.853900817779268f   // (2/EPS)*log2e
#define C10L2E 14.426950408889634f   // (1/EPS)*log2e
#define LN2F   0.6931471805599453f

typedef __attribute__((ext_vector_type(8))) short  sh8;    // 8 x bf16 (4 VGPRs)
typedef __attribute__((ext_vector_type(4))) float  f32x4;  // MFMA C/D

__device__ __forceinline__ float ex2(float x) { return __builtin_amdgcn_exp2f(x); }
__device__ __forceinline__ float lg2(float x) { return __builtin_amdgcn_logf(x); }

// coherent (agent-scope, cache-bypassing) scalar access to cross-block data
__device__ __forceinline__ float coh_load(const float* p) {
  return __uint_as_float(__hip_atomic_load((const unsigned*)p, __ATOMIC_RELAXED,
                                           __HIP_MEMORY_SCOPE_AGENT));
}
__device__ __forceinline__ void coh_store(float* p, float v) {
  __hip_atomic_store((unsigned*)p, __float_as_uint(v), __ATOMIC_RELAXED,
                     __HIP_MEMORY_SCOPE_AGENT);
}

__device__ __forceinline__ unsigned short bf16_rne(float v) {
  unsigned u = __float_as_uint(v);
  unsigned r = (u + 0x7FFFu + ((u >> 16) & 1u)) >> 16;
  return (unsigned short)r;
}

// Split fp32 -> bf16 hi/lo, compute row |.|^2 and initial w2 = 10*log2e*(0 - |.|^2).
__global__ __launch_bounds__(256) void prep_kernel(const float* __restrict__ in,
                                                   unsigned short* __restrict__ hi,
                                                   unsigned short* __restrict__ lo,
                                                   float* __restrict__ snorm,
                                                   float* __restrict__ w2init) {
  const int tid = blockIdx.x * 256 + threadIdx.x;
  const int row = tid >> 5, k = tid & 31;
  float val = in[tid];
  unsigned short h = bf16_rne(val);
  float hf = __uint_as_float(((unsigned)h) << 16);
  unsigned short l = bf16_rne(val - hf);
  hi[tid] = h;
  lo[tid] = l;
  float sq = val * val;
#pragma unroll
  for (int off = 1; off < 32; off <<= 1) sq += __shfl_xor(sq, off, 64);
  if (k == 0) {
    snorm[row] = sq;
    w2init[row] = -sq * C10L2E;
  }
  (void)k;
}

// Per-batch barrier: 64 blocks share one monotonic counter (never reset; the
// target scales with barrier number -> no reset races). Cross-block data
// travels only via coherent atomics, so arrival needs just vmcnt(0) + relaxed
// RMW; the wait spins on relaxed loads (no cache invalidates anywhere).
__device__ __forceinline__ void batch_barrier(int* __restrict__ cnt, int target) {
  __syncthreads();
  if (threadIdx.x == 0) {
    asm volatile("s_waitcnt vmcnt(0)" ::: "memory");
    __hip_atomic_fetch_add(cnt, 1, __ATOMIC_RELAXED, __HIP_MEMORY_SCOPE_AGENT);
    while (__hip_atomic_load(cnt, __ATOMIC_RELAXED, __HIP_MEMORY_SCOPE_AGENT) < target) {
      __builtin_amdgcn_s_sleep(1);
    }
  }
  __syncthreads();
}

// One half-sweep for this block's 32 rows, 512 threads = 8 waves.
// Wave w owns j-eighth w (256 cols), computes BOTH row-groups per B-chunk.
// Opposite dual staged once into LDS via coalesced coherent loads (R7 pattern;
// never per-lane atomic scatter loads -- R8's FETCH explosion).
// FAST=false (it < SAFE_ITERS): exact online LSE (safe for any dual movement);
// tail additionally records the true per-row max into mbArr (LDS).
// FAST=true: shared-bias LSE -- exponent bias = previous same-phase iteration's
// true row max (drift << fp32 exp2 window after warmup). Per element:
// 4 VALU + 1 exp2; reduce tree is plain add + fmax. Mathematically identical
// to max-subtracted LSE (bias exactness not required, only boundedness).
template <bool REC, bool FAST>
__device__ __forceinline__ void sweep_phase(
    const sh8 a0h, const sh8 a0l, const sh8 a1h, const sh8 a1l,
    const unsigned short* __restrict__ Bh, const unsigned short* __restrict__ Bl,
    float* __restrict__ wself2, const float* __restrict__ woth2,
    float* __restrict__ errSlot,
    const int b, const int i0, const float cst, const float sav, float& uold,
    float lm[32][8], float ls[32][8], float* __restrict__ wlds,
    float* __restrict__ mbArr) {
  const int w    = threadIdx.x >> 6;   // j-eighth
  const int lane = threadIdx.x & 63;
  const int l15  = lane & 15, q = lane >> 4;
  const int jbase = w * 256;

  // stage the opposite dual vector (coherent: written by sibling blocks)
#pragma unroll
  for (int idx = 0; idx < NN / 512; idx++)
    wlds[idx * 512 + threadIdx.x] = coh_load(&woth2[b * NN + idx * 512 + threadIdx.x]);

  float mbias[8];
  if (FAST) {
#pragma unroll
    for (int r = 0; r < 8; r++)
      mbias[r] = mbArr[(r < 4) ? (q * 4 + r) : (16 + q * 4 + (r & 3))];
  }

  float m2[8], ss[8];
#pragma unroll
  for (int r = 0; r < 8; r++) { m2[r] = -1e30f; ss[r] = 0.f; }

  __syncthreads();   // wlds ready

#pragma unroll 2
  for (int tj = 0; tj < 16; tj++) {
    const int j = jbase + tj * 16;
    const size_t brow = ((size_t)(b * NN + j + l15)) * DIM + q * 8;
    const sh8 bh = *(const sh8*)(Bh + brow);
    const sh8 bl = *(const sh8*)(Bl + brow);
    f32x4 acc0 = {0.f, 0.f, 0.f, 0.f};
    f32x4 acc1 = {0.f, 0.f, 0.f, 0.f};
    acc0 = __builtin_amdgcn_mfma_f32_16x16x32_bf16(a0h, bh, acc0, 0, 0, 0);
    acc1 = __builtin_amdgcn_mfma_f32_16x16x32_bf16(a1h, bh, acc1, 0, 0, 0);
    acc0 = __builtin_amdgcn_mfma_f32_16x16x32_bf16(a0h, bl, acc0, 0, 0, 0);
    acc1 = __builtin_amdgcn_mfma_f32_16x16x32_bf16(a1h, bl, acc1, 0, 0, 0);
    acc0 = __builtin_amdgcn_mfma_f32_16x16x32_bf16(a0l, bh, acc0, 0, 0, 0);
    acc1 = __builtin_amdgcn_mfma_f32_16x16x32_bf16(a1l, bh, acc1, 0, 0, 0);
    const float wj = wlds[j + l15];
#pragma unroll
    for (int r = 0; r < 8; r++) {
      const float S = (r < 4) ? acc0[r & 3] : acc1[r & 3];
      const float t = fmaf(S, C20L2E, wj);
      if (FAST) {
        ss[r] += ex2(t - mbias[r]);
        m2[r] = fmaxf(m2[r], t);       // exact max tracked for next iteration
      } else {
        const float d = t - m2[r];
        const float e = ex2(-fabsf(d));  // single transcendental
        const bool up = d > 0.f;
        ss[r] = up ? fmaf(ss[r], e, 1.f) : (ss[r] + e);
        m2[r] = fmaxf(m2[r], t);
      }
    }
  }

  // reduce across the 16 lanes that share a row-set
#pragma unroll
  for (int off = 1; off < 16; off <<= 1) {
#pragma unroll
    for (int r = 0; r < 8; r++) {
      if (FAST) {
        ss[r] += __shfl_xor(ss[r], off, 64);                 // shared bias: plain add
        m2[r] = fmaxf(m2[r], __shfl_xor(m2[r], off, 64));
      } else {
        const float mo = __shfl_xor(m2[r], off, 64);
        const float so = __shfl_xor(ss[r], off, 64);
        const float mn = fmaxf(m2[r], mo);
        ss[r] = ss[r] * ex2(m2[r] - mn) + so * ex2(mo - mn);
        m2[r] = mn;
      }
    }
  }

  if (l15 == 0) {
#pragma unroll
    for (int r = 0; r < 4; r++) {
      lm[q * 4 + r][w] = m2[r];          ls[q * 4 + r][w] = ss[r];
      lm[16 + q * 4 + r][w] = m2[4 + r]; ls[16 + q * 4 + r][w] = ss[4 + r];
    }
  }
  __syncthreads();
  if (threadIdx.x < 32) {
    const int row = threadIdx.x;
    float lse;
    if (FAST) {
      float s = 0.f, mnew = -1e30f;
#pragma unroll
      for (int p = 0; p < 8; p++) { s += ls[row][p]; mnew = fmaxf(mnew, lm[row][p]); }
      lse = (mbArr[row] + lg2(s)) * LN2F;   // bias used this phase
      mbArr[row] = mnew;                    // exact max -> next iteration's bias
    } else {
      float m = lm[row][0], s = ls[row][0];
#pragma unroll
      for (int p = 1; p < 8; p++) {
        const float mo = lm[row][p], so = ls[row][p];
        const float mn = fmaxf(m, mo);
        s = s * ex2(m - mn) + so * ex2(mo - mn);
        m = mn;
      }
      lse = (m + lg2(s)) * LN2F;
      mbArr[row] = m;                       // seed bias for the fast path
    }
    const int gi = b * NN + i0 + row;
    const float nu = cst + sav - EPSF * lse;
    coh_store(&wself2[gi], (nu - sav) * C10L2E);
    if (REC) {
      float du = fabsf(nu - uold);
#pragma unroll
      for (int off = 1; off < 32; off <<= 1) du += __shfl_xor(du, off, 64);
      if (threadIdx.x == 0) atomicAdd(errSlot, du);   // device-scope, no reader in loop
      uold = nu;
    }
  }
  __syncthreads();
}

// Persistent kernel: full Sinkhorn loop, one dispatch. 512 WGs x 512 thr
// (2 blocks/CU, 16 waves/CU). b = blk&7 pins each batch to one XCD (512 KB
// read-only panels, L2-resident); barriers are per-batch (64 blocks).
// PASS1: run all MAX_ITER iterations, record err(t,b). PASS2 (rerun for exact
// freeze semantics): run *nIterDev iterations (0 => immediate exit); barrier
// counters continue monotonically from pass 1's 2*MAX_ITER barriers.
template <bool PASS1>
__global__ __launch_bounds__(512, 4) void solve_kernel(
    const unsigned short* __restrict__ xh, const unsigned short* __restrict__ xl,
    const unsigned short* __restrict__ yh, const unsigned short* __restrict__ yl,
    const float* __restrict__ sx, const float* __restrict__ sy,
    float* __restrict__ wu2, float* __restrict__ wv2,
    float* __restrict__ errTab, int* __restrict__ gcnt,
    const int* __restrict__ nIterDev,
    float emu, float enu) {
  __shared__ float lm[32][8];
  __shared__ float ls[32][8];
  __shared__ float wlds[NN];
  __shared__ float mbu[32];
  __shared__ float mbv[32];
  const int b  = blockIdx.x & 7;
  const int i0 = (blockIdx.x >> 3) * 32;
  const int nIter = PASS1 ? MAX_ITER : *nIterDev;
  if (nIter == 0) return;   // pass 2 no-op when pass 1 state is already final

  const int lane = threadIdx.x & 63;
  const int l15 = lane & 15, q = lane >> 4;

  // hoisted loop-invariant A fragments, both row-groups, both phases
  const size_t arow0 = ((size_t)(b * NN + i0 + l15)) * DIM + q * 8;
  const sh8 xa0h = *(const sh8*)(xh + arow0);
  const sh8 xa0l = *(const sh8*)(xl + arow0);
  const sh8 xa1h = *(const sh8*)(xh + arow0 + 16 * DIM);
  const sh8 xa1l = *(const sh8*)(xl + arow0 + 16 * DIM);
  const sh8 ya0h = *(const sh8*)(yh + arow0);
  const sh8 ya0l = *(const sh8*)(yl + arow0);
  const sh8 ya1h = *(const sh8*)(yh + arow0 + 16 * DIM);
  const sh8 ya1l = *(const sh8*)(yl + arow0 + 16 * DIM);

  // per-row constants & previous-u held in registers of the 32 writer threads
  float savx = 0.f, savy = 0.f, uold = 0.f, dummy = 0.f;
  if (threadIdx.x < 32) {
    savx = sx[b * NN + i0 + threadIdx.x];
    savy = sy[b * NN + i0 + threadIdx.x];
  }

  int* cnt = &gcnt[b * 32];
  int tgt = (PASS1 ? 0 : 2 * MAX_ITER) * 64;

  for (int it = 0; it < nIter; ++it) {
    // u-phase: x rows vs all y, weights wv2 -> writes wu2 (+ err in pass 1)
    if (it < SAFE_ITERS)
      sweep_phase<PASS1, false>(xa0h, xa0l, xa1h, xa1l, yh, yl, wu2, wv2,
                                PASS1 ? &errTab[it * BB + b] : wu2,
                                b, i0, emu, savx, uold, lm, ls, wlds, mbu);
    else
      sweep_phase<PASS1, true>(xa0h, xa0l, xa1h, xa1l, yh, yl, wu2, wv2,
                               PASS1 ? &errTab[it * BB + b] : wu2,
                               b, i0, emu, savx, uold, lm, ls, wlds, mbu);
    tgt += 64;
    batch_barrier(cnt, tgt);
    // v-phase: y rows vs all x, weights (updated) wu2 -> writes wv2
    if (it < SAFE_ITERS)
      sweep_phase<false, false>(ya0h, ya0l, ya1h, ya1l, xh, xl, wv2, wu2, wu2,
                                b, i0, enu, savy, dummy, lm, ls, wlds, mbv);
    else
      sweep_phase<false, true>(ya0h, ya0l, ya1h, ya1l, xh, xl, wv2, wu2, wu2,
                               b, i0, enu, savy, dummy, lm, ls, wlds, mbv);
    tgt += 64;
    batch_barrier(cnt, tgt);
  }
}

// Find T* = first iteration with mean-batch err < THRESH. If T* < MAX_ITER-1,
// the reference would have frozen at state(T*): reset duals and request a
// rerun of T*+1 iterations (never taken for inputs that don't converge early).
__global__ __launch_bounds__(256) void tstar_kernel(const float* __restrict__ errTab,
                                                    int* __restrict__ nIterDev,
                                                    const float* __restrict__ sx,
                                                    const float* __restrict__ sy,
                                                    float* __restrict__ wu2,
                                                    float* __restrict__ wv2) {
  __shared__ int best;
  if (threadIdx.x == 0) best = MAX_ITER;
  __syncthreads();
  if (threadIdx.x < MAX_ITER) {
    float e = 0.f;
#pragma unroll
    for (int bb = 0; bb < BB; bb++) e += errTab[threadIdx.x * BB + bb];
    if (e * 0.125f < THRESHF) atomicMin(&best, (int)threadIdx.x);
  }
  __syncthreads();
  const int T = best;
  const int n2 = (T < MAX_ITER - 1) ? T + 1 : 0;
  if (threadIdx.x == 0) *nIterDev = n2;
  if (n2 > 0) {   // reset duals to iteration-0 state for the rerun
    for (int idx = threadIdx.x; idx < BB * NN; idx += 256) {
      wu2[idx] = -sx[idx] * C10L2E;
      wv2[idx] = -sy[idx] * C10L2E;
    }
  }
}

// C = sx_i + sy_j - 2S ; pi = exp2(wu2_i + wv2_j + 20log2e*S) ; cost[b] += pi*C
__global__ __launch_bounds__(256) void finalize_kernel(const unsigned short* __restrict__ xh,
                                                       const unsigned short* __restrict__ xl,
                                                       const unsigned short* __restrict__ yh,
                                                       const unsigned short* __restrict__ yl,
                                                       const float* __restrict__ sx,
                                                       const float* __restrict__ sy,
                                                       const float* __restrict__ wu2,
                                                       const float* __restrict__ wv2,
                                                       float* __restrict__ C,
                                                       float* __restrict__ pi,
                                                       float* __restrict__ cost) {
  const int b  = blockIdx.z;
  const int wv = threadIdx.x >> 6;
  const int lane = threadIdx.x & 63;
  const int l15 = lane & 15, q = lane >> 4;
  const int i0 = blockIdx.y * 128 + wv * 32;
  const int j0 = blockIdx.x * 256;

  const size_t arow0 = ((size_t)(b * NN + i0 + l15)) * DIM + q * 8;
  const sh8 a0h = *(const sh8*)(xh + arow0);
  const sh8 a0l = *(const sh8*)(xl + arow0);
  const sh8 a1h = *(const sh8*)(xh + arow0 + 16 * DIM);
  const sh8 a1l = *(const sh8*)(xl + arow0 + 16 * DIM);

  float sx0[8], wu0[8];
#pragma unroll
  for (int r = 0; r < 8; r++) {
    const int gi = b * NN + i0 + ((r < 4) ? (q * 4 + (r & 3)) : (16 + q * 4 + (r & 3)));
    sx0[r] = sx[gi];
    wu0[r] = wu2[gi];
  }

  float acc = 0.f;
#pragma unroll 2
  for (int tj = 0; tj < 16; tj++) {
    const int j = j0 + tj * 16;
    const size_t brow = ((size_t)(b * NN + j + l15)) * DIM + q * 8;
    const sh8 bh = *(const sh8*)(yh + brow);
    const sh8 bl = *(const sh8*)(yl + brow);
    f32x4 acc0 = {0.f, 0.f, 0.f, 0.f};
    f32x4 acc1 = {0.f, 0.f, 0.f, 0.f};
    acc0 = __builtin_amdgcn_mfma_f32_16x16x32_bf16(a0h, bh, acc0, 0, 0, 0);
    acc1 = __builtin_amdgcn_mfma_f32_16x16x32_bf16(a1h, bh, acc1, 0, 0, 0);
    acc0 = __builtin_amdgcn_mfma_f32_16x16x32_bf16(a0h, bl, acc0, 0, 0, 0);
    acc1 = __builtin_amdgcn_mfma_f32_16x16x32_bf16(a1h, bl, acc1, 0, 0, 0);
    acc0 = __builtin_amdgcn_mfma_f32_16x16x32_bf16(a0l, bh, acc0, 0, 0, 0);
    acc1 = __builtin_amdgcn_mfma_f32_16x16x32_bf16(a1l, bh, acc1, 0, 0, 0);
    const int gj = b * NN + j + l15;
    const float syj = sy[gj];
    const float wvj = wv2[gj];
#pragma unroll
    for (int r = 0; r < 8; r++) {
      const float S = (r < 4) ? acc0[r & 3] : acc1[r & 3];
      const int irow = i0 + ((r < 4) ? (q * 4 + (r & 3)) : (16 + q * 4 + (r & 3)));
      const float Cv = fmaf(-2.f, S, sx0[r] + syj);
      const float p  = ex2(fmaf(S, C20L2E, wu0[r] + wvj));
      const size_t addr = ((size_t)(b * NN + irow)) * NN + j + l15;
      C[addr]  = Cv;
      pi[addr] = p;
      acc = fmaf(p, Cv, acc);
    }
  }
#pragma unroll
  for (int off = 1; off < 64; off <<= 1) acc += __shfl_xor(acc, off, 64);
  __shared__ float red[4];
  if (lane == 0) red[wv] = acc;
  __syncthreads();
  if (threadIdx.x == 0) atomicAdd(&cost[b], red[0] + red[1] + red[2] + red[3]);
}

extern "C" void kernel_launch(void* const* d_in, const int* in_sizes, int n_in,
                              void* d_out, int out_size, void* d_ws, size_t ws_size,
                              hipStream_t stream) {
  const float* x = (const float*)d_in[0];
  const float* y = (const float*)d_in[1];
  float* out  = (float*)d_out;
  float* cost = out;                              // [8]
  float* pi   = out + 8;                          // [8,2048,2048]
  float* C    = out + 8 + (size_t)BB * NN * NN;   // [8,2048,2048]

  float* ws = (float*)d_ws;
  const int BN = BB * NN;                         // 16384
  float* wu2 = ws;                                // [16384]
  float* wv2 = ws + BN;
  float* sx  = ws + 2 * BN;
  float* sy  = ws + 3 * BN;
  float* errTab = ws + 4 * BN;                    // [100*8], zeroed
  int*   gcnt   = (int*)(ws + 4 * BN + 1024);     // 8 counters, stride 32 ints
  int*   nIterDev = (int*)(ws + 4 * BN + 1280);
  unsigned short* xh = (unsigned short*)(ws + 4 * BN + 1536);
  const size_t NE = (size_t)BB * NN * DIM;        // 524288
  unsigned short* xl = xh + NE;
  unsigned short* yh = xh + 2 * NE;
  unsigned short* yl = xh + 3 * NE;

  // zero errTab + barrier counters + nIter (prep rewrites wu2/wv2/sx/sy)
  hipMemsetAsync(errTab, 0, 1536 * sizeof(float), stream);
  hipMemsetAsync(d_out, 0, 8 * sizeof(float), stream);

  prep_kernel<<<2048, 256, 0, stream>>>(x, xh, xl, sx, wu2);
  prep_kernel<<<2048, 256, 0, stream>>>(y, yh, yl, sy, wv2);

  const float emu = (float)(0.1 * log(1.0 / 2048.0 + 1e-8));
  const float enu = emu;

  solve_kernel<true><<<512, 512, 0, stream>>>(xh, xl, yh, yl, sx, sy, wu2, wv2,
                                              errTab, gcnt, nIterDev, emu, enu);
  tstar_kernel<<<1, 256, 0, stream>>>(errTab, nIterDev, sx, sy, wu2, wv2);
  solve_kernel<false><<<512, 512, 0, stream>>>(xh, xl, yh, yl, sx, sy, wu2, wv2,
                                               errTab, gcnt, nIterDev, emu, enu);

  finalize_kernel<<<dim3(8, 16, BB), 256, 0, stream>>>(xh, xl, yh, yl, sx, sy,
                                                       wu2, wv2, C, pi, cost);
}

// Round 10
// 3294.888 us; speedup vs baseline: 1.5330x; 1.0998x over previous
//
#include <hip/hip_runtime.h>
#include <math.h>

#define EPSF     0.1f
#define BB       8
#define NN       2048
#define DIM      32
#define MAX_ITER 100
#define THRESHF  0.1f
#define SAFE_ITERS 6
// base-2 domain constants: exp(x) = exp2(x*log2e)
#define C20L2E 28.853900817779268f   // (2/EPS)*log2e
#define C10L2E 14.426950408889634f   // (1/EPS)*log2e
#define LN2F   0.6931471805599453f
#define M2INV  -0.06931471805599453f // -2/C20L2E = -0.1*ln2

typedef __attribute__((ext_vector_type(8))) short  sh8;    // 8 x bf16 (4 VGPRs)
typedef __attribute__((ext_vector_type(4))) float  f32x4;  // MFMA C/D

__device__ __forceinline__ float ex2(float x) { return __builtin_amdgcn_exp2f(x); }
__device__ __forceinline__ float lg2(float x) { return __builtin_amdgcn_logf(x); }

// coherent (agent-scope, cache-bypassing) scalar access to cross-block data
__device__ __forceinline__ float coh_load(const float* p) {
  return __uint_as_float(__hip_atomic_load((const unsigned*)p, __ATOMIC_RELAXED,
                                           __HIP_MEMORY_SCOPE_AGENT));
}
__device__ __forceinline__ void coh_store(float* p, float v) {
  __hip_atomic_store((unsigned*)p, __float_as_uint(v), __ATOMIC_RELAXED,
                     __HIP_MEMORY_SCOPE_AGENT);
}

__device__ __forceinline__ unsigned short bf16_rne(float v) {
  unsigned u = __float_as_uint(v);
  unsigned r = (u + 0x7FFFu + ((u >> 16) & 1u)) >> 16;
  return (unsigned short)r;
}

// Split (scale*val) fp32 -> bf16 hi/lo; row |val|^2 and w2 = -|val|^2 * C10L2E.
// X panels are pre-scaled by C20L2E so MFMA emits S' = 20*log2e*S directly
// (only one operand side may be scaled; every product in this pipeline
// contains x exactly once, so scaling x covers u-phase, v-phase AND finalize).
__global__ __launch_bounds__(256) void prep_kernel(const float* __restrict__ in,
                                                   unsigned short* __restrict__ hi,
                                                   unsigned short* __restrict__ lo,
                                                   float* __restrict__ snorm,
                                                   float* __restrict__ w2init,
                                                   float scale) {
  const int tid = blockIdx.x * 256 + threadIdx.x;
  const int row = tid >> 5, k = tid & 31;
  float val = in[tid];
  float vs = val * scale;
  unsigned short h = bf16_rne(vs);
  float hf = __uint_as_float(((unsigned)h) << 16);
  unsigned short l = bf16_rne(vs - hf);
  hi[tid] = h;
  lo[tid] = l;
  float sq = val * val;
#pragma unroll
  for (int off = 1; off < 32; off <<= 1) sq += __shfl_xor(sq, off, 64);
  if (k == 0) {
    snorm[row] = sq;
    w2init[row] = -sq * C10L2E;
  }
  (void)k;
}

// Per-batch barrier: 64 blocks share one monotonic counter (never reset; the
// target scales with barrier number -> no reset races). Cross-block data
// travels only via coherent atomics, so arrival needs just vmcnt(0) + relaxed
// RMW; the wait spins on relaxed loads (no cache invalidates anywhere).
__device__ __forceinline__ void batch_barrier(int* __restrict__ cnt, int target) {
  __syncthreads();
  if (threadIdx.x == 0) {
    asm volatile("s_waitcnt vmcnt(0)" ::: "memory");
    __hip_atomic_fetch_add(cnt, 1, __ATOMIC_RELAXED, __HIP_MEMORY_SCOPE_AGENT);
    while (__hip_atomic_load(cnt, __ATOMIC_RELAXED, __HIP_MEMORY_SCOPE_AGENT) < target) {
      __builtin_amdgcn_s_sleep(1);
    }
  }
  __syncthreads();
}

// One half-sweep for this block's 32 rows, 512 threads = 8 waves; wave w owns
// j-eighth w, both row-groups per B-chunk. MFMA output IS the exp2 argument:
// accumulator initialized to (wj - bias[r]); S' arrives pre-scaled by C20L2E.
// FAST (it >= SAFE_ITERS): bias-LSE. lse2 = bias + lg2(sum exp2(t - bias)) is
// EXACT for any bounded bias (telescopes); bias := previous same-phase lse2 ->
// args in [-log2(N)-drift, drift]. Per element: ss += ex2(acc) only.
// No per-element max, no m-half of the reduce tree (shuffle count halved).
// SAFE (it < SAFE_ITERS): guarded online LSE; seeds bias with exact lse2.
template <bool REC, bool FAST>
__device__ __forceinline__ void sweep_phase(
    const sh8 a0h, const sh8 a0l, const sh8 a1h, const sh8 a1l,
    const unsigned short* __restrict__ Bh, const unsigned short* __restrict__ Bl,
    float* __restrict__ wself2, const float* __restrict__ woth2,
    float* __restrict__ errSlot,
    const int b, const int i0, const float cst, const float sav, float& uold,
    float lm[32][8], float ls[32][8], float* __restrict__ wlds,
    float* __restrict__ mbArr) {
  const int w    = threadIdx.x >> 6;   // j-eighth
  const int lane = threadIdx.x & 63;
  const int l15  = lane & 15, q = lane >> 4;
  const int jbase = w * 256;

  // stage the opposite dual vector (coherent: written by sibling blocks)
#pragma unroll
  for (int idx = 0; idx < NN / 512; idx++)
    wlds[idx * 512 + threadIdx.x] = coh_load(&woth2[b * NN + idx * 512 + threadIdx.x]);

  float mbias[8];
  if (FAST) {
#pragma unroll
    for (int r = 0; r < 8; r++)
      mbias[r] = mbArr[(r < 4) ? (q * 4 + r) : (16 + q * 4 + (r & 3))];
  }

  float m2[8], ss[8];
#pragma unroll
  for (int r = 0; r < 8; r++) { m2[r] = -1e30f; ss[r] = 0.f; }

  __syncthreads();   // wlds ready

#pragma unroll 2
  for (int tj = 0; tj < 16; tj++) {
    const int j = jbase + tj * 16;
    const size_t brow = ((size_t)(b * NN + j + l15)) * DIM + q * 8;
    const sh8 bh = *(const sh8*)(Bh + brow);
    const sh8 bl = *(const sh8*)(Bl + brow);
    const float wj = wlds[j + l15];
    f32x4 acc0, acc1;
    if (FAST) {
      acc0[0] = wj - mbias[0]; acc0[1] = wj - mbias[1];
      acc0[2] = wj - mbias[2]; acc0[3] = wj - mbias[3];
      acc1[0] = wj - mbias[4]; acc1[1] = wj - mbias[5];
      acc1[2] = wj - mbias[6]; acc1[3] = wj - mbias[7];
    } else {
      acc0[0] = wj; acc0[1] = wj; acc0[2] = wj; acc0[3] = wj;
      acc1 = acc0;
    }
    acc0 = __builtin_amdgcn_mfma_f32_16x16x32_bf16(a0h, bh, acc0, 0, 0, 0);
    acc1 = __builtin_amdgcn_mfma_f32_16x16x32_bf16(a1h, bh, acc1, 0, 0, 0);
    acc0 = __builtin_amdgcn_mfma_f32_16x16x32_bf16(a0h, bl, acc0, 0, 0, 0);
    acc1 = __builtin_amdgcn_mfma_f32_16x16x32_bf16(a1h, bl, acc1, 0, 0, 0);
    acc0 = __builtin_amdgcn_mfma_f32_16x16x32_bf16(a0l, bh, acc0, 0, 0, 0);
    acc1 = __builtin_amdgcn_mfma_f32_16x16x32_bf16(a1l, bh, acc1, 0, 0, 0);
#pragma unroll
    for (int r = 0; r < 8; r++) {
      const float t = (r < 4) ? acc0[r & 3] : acc1[r & 3];
      if (FAST) {
        ss[r] += ex2(t);                 // t already = S' + wj - bias
      } else {
        const float d = t - m2[r];
        const float e = ex2(-fabsf(d));  // single transcendental
        const bool up = d > 0.f;
        ss[r] = up ? fmaf(ss[r], e, 1.f) : (ss[r] + e);
        m2[r] = fmaxf(m2[r], t);
      }
    }
  }

  // reduce across the 16 lanes that share a row-set
#pragma unroll
  for (int off = 1; off < 16; off <<= 1) {
#pragma unroll
    for (int r = 0; r < 8; r++) {
      if (FAST) {
        ss[r] += __shfl_xor(ss[r], off, 64);   // shared bias: plain add only
      } else {
        const float mo = __shfl_xor(m2[r], off, 64);
        const float so = __shfl_xor(ss[r], off, 64);
        const float mn = fmaxf(m2[r], mo);
        ss[r] = ss[r] * ex2(m2[r] - mn) + so * ex2(mo - mn);
        m2[r] = mn;
      }
    }
  }

  if (l15 == 0) {
#pragma unroll
    for (int r = 0; r < 4; r++) {
      ls[q * 4 + r][w] = ss[r];
      ls[16 + q * 4 + r][w] = ss[4 + r];
      if (!FAST) {
        lm[q * 4 + r][w] = m2[r];
        lm[16 + q * 4 + r][w] = m2[4 + r];
      }
    }
  }
  __syncthreads();
  if (threadIdx.x < 32) {
    const int row = threadIdx.x;
    float lse2;
    if (FAST) {
      float s = 0.f;
#pragma unroll
      for (int p = 0; p < 8; p++) s += ls[row][p];
      lse2 = mbArr[row] + lg2(s);          // exact: telescopes over the bias
    } else {
      float m = lm[row][0], s = ls[row][0];
#pragma unroll
      for (int p = 1; p < 8; p++) {
        const float mo = lm[row][p], so = ls[row][p];
        const float mn = fmaxf(m, mo);
        s = s * ex2(m - mn) + so * ex2(mo - mn);
        m = mn;
      }
      lse2 = m + lg2(s);
    }
    mbArr[row] = lse2;                     // next same-phase iteration's bias
    const float lse = lse2 * LN2F;         // natural-log LSE
    const int gi = b * NN + i0 + row;
    const float nu = cst + sav - EPSF * lse;
    coh_store(&wself2[gi], (nu - sav) * C10L2E);
    if (REC) {
      float du = fabsf(nu - uold);
#pragma unroll
      for (int off = 1; off < 32; off <<= 1) du += __shfl_xor(du, off, 64);
      if (threadIdx.x == 0) atomicAdd(errSlot, du);   // device-scope, no reader in loop
      uold = nu;
    }
  }
  __syncthreads();
}

// Persistent kernel: full Sinkhorn loop, one dispatch. 512 WGs x 512 thr
// (2 blocks/CU, 16 waves/CU). b = blk&7 pins each batch to one XCD (512 KB
// read-only panels, L2-resident); barriers are per-batch (64 blocks).
// PASS1: run all MAX_ITER iterations, record err(t,b). PASS2 (rerun for exact
// freeze semantics): run *nIterDev iterations (0 => immediate exit, the case
// for non-early-converging inputs); replay is bit-deterministic.
template <bool PASS1>
__global__ __launch_bounds__(512, 4) void solve_kernel(
    const unsigned short* __restrict__ xh, const unsigned short* __restrict__ xl,
    const unsigned short* __restrict__ yh, const unsigned short* __restrict__ yl,
    const float* __restrict__ sx, const float* __restrict__ sy,
    float* __restrict__ wu2, float* __restrict__ wv2,
    float* __restrict__ errTab, int* __restrict__ gcnt,
    const int* __restrict__ nIterDev,
    float emu, float enu) {
  __shared__ float lm[32][8];
  __shared__ float ls[32][8];
  __shared__ float wlds[NN];
  __shared__ float mbu[32];
  __shared__ float mbv[32];
  const int b  = blockIdx.x & 7;
  const int i0 = (blockIdx.x >> 3) * 32;
  const int nIter = PASS1 ? MAX_ITER : *nIterDev;
  if (nIter == 0) return;   // pass 2 no-op when pass 1 state is already final

  const int lane = threadIdx.x & 63;
  const int l15 = lane & 15, q = lane >> 4;

  // hoisted loop-invariant A fragments, both row-groups, both phases
  const size_t arow0 = ((size_t)(b * NN + i0 + l15)) * DIM + q * 8;
  const sh8 xa0h = *(const sh8*)(xh + arow0);
  const sh8 xa0l = *(const sh8*)(xl + arow0);
  const sh8 xa1h = *(const sh8*)(xh + arow0 + 16 * DIM);
  const sh8 xa1l = *(const sh8*)(xl + arow0 + 16 * DIM);
  const sh8 ya0h = *(const sh8*)(yh + arow0);
  const sh8 ya0l = *(const sh8*)(yl + arow0);
  const sh8 ya1h = *(const sh8*)(yh + arow0 + 16 * DIM);
  const sh8 ya1l = *(const sh8*)(yl + arow0 + 16 * DIM);

  // per-row constants & previous-u held in registers of the 32 writer threads
  float savx = 0.f, savy = 0.f, uold = 0.f, dummy = 0.f;
  if (threadIdx.x < 32) {
    savx = sx[b * NN + i0 + threadIdx.x];
    savy = sy[b * NN + i0 + threadIdx.x];
  }

  int* cnt = &gcnt[b * 32];
  int tgt = (PASS1 ? 0 : 2 * MAX_ITER) * 64;

  for (int it = 0; it < nIter; ++it) {
    // u-phase: x rows vs all y, weights wv2 -> writes wu2 (+ err in pass 1)
    if (it < SAFE_ITERS)
      sweep_phase<PASS1, false>(xa0h, xa0l, xa1h, xa1l, yh, yl, wu2, wv2,
                                PASS1 ? &errTab[it * BB + b] : wu2,
                                b, i0, emu, savx, uold, lm, ls, wlds, mbu);
    else
      sweep_phase<PASS1, true>(xa0h, xa0l, xa1h, xa1l, yh, yl, wu2, wv2,
                               PASS1 ? &errTab[it * BB + b] : wu2,
                               b, i0, emu, savx, uold, lm, ls, wlds, mbu);
    tgt += 64;
    batch_barrier(cnt, tgt);
    // v-phase: y rows vs all x (x panels carry the C20L2E scale) -> writes wv2
    if (it < SAFE_ITERS)
      sweep_phase<false, false>(ya0h, ya0l, ya1h, ya1l, xh, xl, wv2, wu2, wu2,
                                b, i0, enu, savy, dummy, lm, ls, wlds, mbv);
    else
      sweep_phase<false, true>(ya0h, ya0l, ya1h, ya1l, xh, xl, wv2, wu2, wu2,
                               b, i0, enu, savy, dummy, lm, ls, wlds, mbv);
    tgt += 64;
    batch_barrier(cnt, tgt);
  }
}

// Find T* = first iteration with mean-batch err < THRESH. If T* < MAX_ITER-1,
// the reference would have frozen at state(T*): reset duals and request a
// rerun of T*+1 iterations (never taken for inputs that don't converge early).
__global__ __launch_bounds__(256) void tstar_kernel(const float* __restrict__ errTab,
                                                    int* __restrict__ nIterDev,
                                                    const float* __restrict__ sx,
                                                    const float* __restrict__ sy,
                                                    float* __restrict__ wu2,
                                                    float* __restrict__ wv2) {
  __shared__ int best;
  if (threadIdx.x == 0) best = MAX_ITER;
  __syncthreads();
  if (threadIdx.x < MAX_ITER) {
    float e = 0.f;
#pragma unroll
    for (int bb = 0; bb < BB; bb++) e += errTab[threadIdx.x * BB + bb];
    if (e * 0.125f < THRESHF) atomicMin(&best, (int)threadIdx.x);
  }
  __syncthreads();
  const int T = best;
  const int n2 = (T < MAX_ITER - 1) ? T + 1 : 0;
  if (threadIdx.x == 0) *nIterDev = n2;
  if (n2 > 0) {   // reset duals to iteration-0 state for the rerun
    for (int idx = threadIdx.x; idx < BB * NN; idx += 256) {
      wu2[idx] = -sx[idx] * C10L2E;
      wv2[idx] = -sy[idx] * C10L2E;
    }
  }
}

// S' = C20L2E*S (x panels pre-scaled). C = sx+sy-2S = fmaf(M2INV,S',sx+sy);
// pi = exp2(S' + wu2 + wv2); cost[b] += pi*C.
__global__ __launch_bounds__(256) void finalize_kernel(const unsigned short* __restrict__ xh,
                                                       const unsigned short* __restrict__ xl,
                                                       const unsigned short* __restrict__ yh,
                                                       const unsigned short* __restrict__ yl,
                                                       const float* __restrict__ sx,
                                                       const float* __restrict__ sy,
                                                       const float* __restrict__ wu2,
                                                       const float* __restrict__ wv2,
                                                       float* __restrict__ C,
                                                       float* __restrict__ pi,
                                                       float* __restrict__ cost) {
  const int b  = blockIdx.z;
  const int wv = threadIdx.x >> 6;
  const int lane = threadIdx.x & 63;
  const int l15 = lane & 15, q = lane >> 4;
  const int i0 = blockIdx.y * 128 + wv * 32;
  const int j0 = blockIdx.x * 256;

  const size_t arow0 = ((size_t)(b * NN + i0 + l15)) * DIM + q * 8;
  const sh8 a0h = *(const sh8*)(xh + arow0);
  const sh8 a0l = *(const sh8*)(xl + arow0);
  const sh8 a1h = *(const sh8*)(xh + arow0 + 16 * DIM);
  const sh8 a1l = *(const sh8*)(xl + arow0 + 16 * DIM);

  float sx0[8], wu0[8];
#pragma unroll
  for (int r = 0; r < 8; r++) {
    const int gi = b * NN + i0 + ((r < 4) ? (q * 4 + (r & 3)) : (16 + q * 4 + (r & 3)));
    sx0[r] = sx[gi];
    wu0[r] = wu2[gi];
  }

  float acc = 0.f;
#pragma unroll 2
  for (int tj = 0; tj < 16; tj++) {
    const int j = j0 + tj * 16;
    const size_t brow = ((size_t)(b * NN + j + l15)) * DIM + q * 8;
    const sh8 bh = *(const sh8*)(yh + brow);
    const sh8 bl = *(const sh8*)(yl + brow);
    f32x4 acc0 = {0.f, 0.f, 0.f, 0.f};
    f32x4 acc1 = {0.f, 0.f, 0.f, 0.f};
    acc0 = __builtin_amdgcn_mfma_f32_16x16x32_bf16(a0h, bh, acc0, 0, 0, 0);
    acc1 = __builtin_amdgcn_mfma_f32_16x16x32_bf16(a1h, bh, acc1, 0, 0, 0);
    acc0 = __builtin_amdgcn_mfma_f32_16x16x32_bf16(a0h, bl, acc0, 0, 0, 0);
    acc1 = __builtin_amdgcn_mfma_f32_16x16x32_bf16(a1h, bl, acc1, 0, 0, 0);
    acc0 = __builtin_amdgcn_mfma_f32_16x16x32_bf16(a0l, bh, acc0, 0, 0, 0);
    acc1 = __builtin_amdgcn_mfma_f32_16x16x32_bf16(a1l, bh, acc1, 0, 0, 0);
    const int gj = b * NN + j + l15;
    const float syj = sy[gj];
    const float wvj = wv2[gj];
#pragma unroll
    for (int r = 0; r < 8; r++) {
      const float Sp = (r < 4) ? acc0[r & 3] : acc1[r & 3];   // = C20L2E * S
      const int irow = i0 + ((r < 4) ? (q * 4 + (r & 3)) : (16 + q * 4 + (r & 3)));
      const float Cv = fmaf(M2INV, Sp, sx0[r] + syj);
      const float p  = ex2(Sp + (wu0[r] + wvj));
      const size_t addr = ((size_t)(b * NN + irow)) * NN + j + l15;
      C[addr]  = Cv;
      pi[addr] = p;
      acc = fmaf(p, Cv, acc);
    }
  }
#pragma unroll
  for (int off = 1; off < 64; off <<= 1) acc += __shfl_xor(acc, off, 64);
  __shared__ float red[4];
  if (lane == 0) red[wv] = acc;
  __syncthreads();
  if (threadIdx.x == 0) atomicAdd(&cost[b], red[0] + red[1] + red[2] + red[3]);
}

extern "C" void kernel_launch(void* const* d_in, const int* in_sizes, int n_in,
                              void* d_out, int out_size, void* d_ws, size_t ws_size,
                              hipStream_t stream) {
  const float* x = (const float*)d_in[0];
  const float* y = (const float*)d_in[1];
  float* out  = (float*)d_out;
  float* cost = out;                              // [8]
  float* pi   = out + 8;                          // [8,2048,2048]
  float* C    = out + 8 + (size_t)BB * NN * NN;   // [8,2048,2048]

  float* ws = (float*)d_ws;
  const int BN = BB * NN;                         // 16384
  float* wu2 = ws;                                // [16384]
  float* wv2 = ws + BN;
  float* sx  = ws + 2 * BN;
  float* sy  = ws + 3 * BN;
  float* errTab = ws + 4 * BN;                    // [100*8], zeroed
  int*   gcnt   = (int*)(ws + 4 * BN + 1024);     // 8 counters, stride 32 ints
  int*   nIterDev = (int*)(ws + 4 * BN + 1280);
  unsigned short* xh = (unsigned short*)(ws + 4 * BN + 1536);
  const size_t NE = (size_t)BB * NN * DIM;        // 524288
  unsigned short* xl = xh + NE;
  unsigned short* yh = xh + 2 * NE;
  unsigned short* yl = xh + 3 * NE;

  // zero errTab + barrier counters + nIter (prep rewrites wu2/wv2/sx/sy)
  hipMemsetAsync(errTab, 0, 1536 * sizeof(float), stream);
  hipMemsetAsync(d_out, 0, 8 * sizeof(float), stream);

  prep_kernel<<<2048, 256, 0, stream>>>(x, xh, xl, sx, wu2, C20L2E);  // x scaled
  prep_kernel<<<2048, 256, 0, stream>>>(y, yh, yl, sy, wv2, 1.0f);    // y unscaled

  const float emu = (float)(0.1 * log(1.0 / 2048.0 + 1e-8));
  const float enu = emu;

  solve_kernel<true><<<512, 512, 0, stream>>>(xh, xl, yh, yl, sx, sy, wu2, wv2,
                                              errTab, gcnt, nIterDev, emu, enu);
  tstar_kernel<<<1, 256, 0, stream>>>(errTab, nIterDev, sx, sy, wu2, wv2);
  solve_kernel<false><<<512, 512, 0, stream>>>(xh, xl, yh, yl, sx, sy, wu2, wv2,
                                               errTab, gcnt, nIterDev, emu, enu);

  finalize_kernel<<<dim3(8, 16, BB), 256, 0, stream>>>(xh, xl, yh, yl, sx, sy,
                                                       wu2, wv2, C, pi, cost);
}

// Round 11
// 2726.005 us; speedup vs baseline: 1.8530x; 1.2087x over previous
//
#include <hip/hip_runtime.h>
#include <math.h>

#define EPSF     0.1f
#define BB       8
#define NN       2048
#define DIM      32
#define MAX_ITER 100
#define THRESHF  0.1f
#define SAFE_ITERS 6
#define BPB      32   // blocks per batch (256 total)
// base-2 domain constants: exp(x) = exp2(x*log2e)
#define C20L2E 28.853900817779268f   // (2/EPS)*log2e
#define C10L2E 14.426950408889634f   // (1/EPS)*log2e
#define LN2F   0.6931471805599453f
#define M2INV  -0.06931471805599453f // -2/C20L2E = -0.1*ln2

typedef __attribute__((ext_vector_type(8))) short  sh8;    // 8 x bf16 (4 VGPRs)
typedef __attribute__((ext_vector_type(4))) float  f32x4;  // MFMA C/D

__device__ __forceinline__ float ex2(float x) { return __builtin_amdgcn_exp2f(x); }
__device__ __forceinline__ float lg2(float x) { return __builtin_amdgcn_logf(x); }

// coherent (agent-scope, cache-bypassing) access to cross-block data
__device__ __forceinline__ float coh_load(const float* p) {
  return __uint_as_float(__hip_atomic_load((const unsigned*)p, __ATOMIC_RELAXED,
                                           __HIP_MEMORY_SCOPE_AGENT));
}
__device__ __forceinline__ void coh_store(float* p, float v) {
  __hip_atomic_store((unsigned*)p, __float_as_uint(v), __ATOMIC_RELAXED,
                     __HIP_MEMORY_SCOPE_AGENT);
}

__device__ __forceinline__ unsigned short bf16_rne(float v) {
  unsigned u = __float_as_uint(v);
  unsigned r = (u + 0x7FFFu + ((u >> 16) & 1u)) >> 16;
  return (unsigned short)r;
}

// Split (scale*val) fp32 -> bf16 hi/lo; row |val|^2 and w2 = -|val|^2 * C10L2E.
// X panels pre-scaled by C20L2E so MFMA emits S' = 20*log2e*S directly.
__global__ __launch_bounds__(256) void prep_kernel(const float* __restrict__ in,
                                                   unsigned short* __restrict__ hi,
                                                   unsigned short* __restrict__ lo,
                                                   float* __restrict__ snorm,
                                                   float* __restrict__ w2init,
                                                   float scale) {
  const int tid = blockIdx.x * 256 + threadIdx.x;
  const int row = tid >> 5, k = tid & 31;
  float val = in[tid];
  float vs = val * scale;
  unsigned short h = bf16_rne(vs);
  float hf = __uint_as_float(((unsigned)h) << 16);
  unsigned short l = bf16_rne(vs - hf);
  hi[tid] = h;
  lo[tid] = l;
  float sq = val * val;
#pragma unroll
  for (int off = 1; off < 32; off <<= 1) sq += __shfl_xor(sq, off, 64);
  if (k == 0) {
    snorm[row] = sq;
    w2init[row] = -sq * C10L2E;
  }
  (void)k;
}

// Per-batch barrier: BPB blocks share one monotonic counter (never reset; the
// target scales with barrier number -> no reset races). Cross-block data
// travels only via coherent atomics, so arrival needs just vmcnt(0) + relaxed
// RMW; the wait spins on relaxed loads (no cache invalidates anywhere).
__device__ __forceinline__ void batch_barrier(int* __restrict__ cnt, int target) {
  __syncthreads();
  if (threadIdx.x == 0) {
    asm volatile("s_waitcnt vmcnt(0)" ::: "memory");
    __hip_atomic_fetch_add(cnt, 1, __ATOMIC_RELAXED, __HIP_MEMORY_SCOPE_AGENT);
    while (__hip_atomic_load(cnt, __ATOMIC_RELAXED, __HIP_MEMORY_SCOPE_AGENT) < target) {
      __builtin_amdgcn_s_sleep(1);
    }
  }
  __syncthreads();
}

// One half-sweep for this block's 64 rows, 512 threads = 8 waves; wave w owns
// j-eighth w (256 cols) and computes FOUR row-groups per B-chunk (12 MFMA +
// 16 exp2 per chunk). Per-CU compute identical to the 32-row/2-block layout;
// per-block fixed costs (staging, barrier arrival, tail) are amortized 2x.
// Opposite dual staged once into LDS via coalesced 8B coherent loads.
// MFMA accumulator is initialized to (wj - bias[r]) so its output IS the exp2
// argument (x panels carry the C20L2E scale).
// FAST: bias-LSE (exact for any bounded bias; bias = previous same-phase lse2).
// SAFE (it < SAFE_ITERS): guarded online LSE; seeds the bias.
template <bool REC, bool FAST>
__device__ __forceinline__ void sweep_phase(
    const unsigned short* __restrict__ Ah, const unsigned short* __restrict__ Al,
    const unsigned short* __restrict__ Bh, const unsigned short* __restrict__ Bl,
    float* __restrict__ wself2, const float* __restrict__ woth2,
    float* __restrict__ errSlot,
    const int b, const int i0, const float cst, const float sav, float& uold,
    float lm[64][8], float ls[64][8], float* __restrict__ wlds,
    float* __restrict__ mbArr) {
  const int w    = threadIdx.x >> 6;   // j-eighth
  const int lane = threadIdx.x & 63;
  const int l15  = lane & 15, q = lane >> 4;
  const int jbase = w * 256;

  // stage the opposite dual vector: 2048 floats as 1024 x 8B coherent loads
  {
    const unsigned long long* src = (const unsigned long long*)(woth2 + b * NN);
    unsigned long long* dst = (unsigned long long*)wlds;
#pragma unroll
    for (int idx = 0; idx < 2; idx++)
      dst[idx * 512 + threadIdx.x] =
          __hip_atomic_load(src + idx * 512 + threadIdx.x, __ATOMIC_RELAXED,
                            __HIP_MEMORY_SCOPE_AGENT);
  }

  // this phase's A fragments (L2-hot panels; overlaps the staging latency)
  const size_t abase = ((size_t)(b * NN + i0 + l15)) * DIM + q * 8;
  sh8 ah[4], al[4];
#pragma unroll
  for (int g = 0; g < 4; g++) {
    ah[g] = *(const sh8*)(Ah + abase + (size_t)g * 16 * DIM);
    al[g] = *(const sh8*)(Al + abase + (size_t)g * 16 * DIM);
  }

  float mbias[16];
  if (FAST) {
#pragma unroll
    for (int r = 0; r < 16; r++)
      mbias[r] = mbArr[(r >> 2) * 16 + q * 4 + (r & 3)];
  }

  float m2[16], ss[16];
#pragma unroll
  for (int r = 0; r < 16; r++) { m2[r] = -1e30f; ss[r] = 0.f; }

  __syncthreads();   // wlds ready

#pragma unroll 2
  for (int tj = 0; tj < 16; tj++) {
    const int j = jbase + tj * 16;
    const size_t brow = ((size_t)(b * NN + j + l15)) * DIM + q * 8;
    const sh8 bh = *(const sh8*)(Bh + brow);
    const sh8 bl = *(const sh8*)(Bl + brow);
    const float wj = wlds[j + l15];
    f32x4 acc[4];
#pragma unroll
    for (int g = 0; g < 4; g++) {
      if (FAST) {
        acc[g][0] = wj - mbias[g * 4 + 0];
        acc[g][1] = wj - mbias[g * 4 + 1];
        acc[g][2] = wj - mbias[g * 4 + 2];
        acc[g][3] = wj - mbias[g * 4 + 3];
      } else {
        acc[g][0] = wj; acc[g][1] = wj; acc[g][2] = wj; acc[g][3] = wj;
      }
    }
#pragma unroll
    for (int g = 0; g < 4; g++)
      acc[g] = __builtin_amdgcn_mfma_f32_16x16x32_bf16(ah[g], bh, acc[g], 0, 0, 0);
#pragma unroll
    for (int g = 0; g < 4; g++)
      acc[g] = __builtin_amdgcn_mfma_f32_16x16x32_bf16(ah[g], bl, acc[g], 0, 0, 0);
#pragma unroll
    for (int g = 0; g < 4; g++)
      acc[g] = __builtin_amdgcn_mfma_f32_16x16x32_bf16(al[g], bh, acc[g], 0, 0, 0);
#pragma unroll
    for (int r = 0; r < 16; r++) {
      const float t = acc[r >> 2][r & 3];
      if (FAST) {
        ss[r] += ex2(t);                 // t already = S' + wj - bias
      } else {
        const float d = t - m2[r];
        const float e = ex2(-fabsf(d));  // single transcendental
        const bool up = d > 0.f;
        ss[r] = up ? fmaf(ss[r], e, 1.f) : (ss[r] + e);
        m2[r] = fmaxf(m2[r], t);
      }
    }
  }

  // reduce across the 16 lanes that share a row-set
#pragma unroll
  for (int off = 1; off < 16; off <<= 1) {
#pragma unroll
    for (int r = 0; r < 16; r++) {
      if (FAST) {
        ss[r] += __shfl_xor(ss[r], off, 64);   // shared bias: plain add only
      } else {
        const float mo = __shfl_xor(m2[r], off, 64);
        const float so = __shfl_xor(ss[r], off, 64);
        const float mn = fmaxf(m2[r], mo);
        ss[r] = ss[r] * ex2(m2[r] - mn) + so * ex2(mo - mn);
        m2[r] = mn;
      }
    }
  }

  if (l15 == 0) {
#pragma unroll
    for (int r = 0; r < 16; r++) {
      const int row = (r >> 2) * 16 + q * 4 + (r & 3);
      ls[row][w] = ss[r];
      if (!FAST) lm[row][w] = m2[r];
    }
  }
  __syncthreads();
  if (threadIdx.x < 64) {
    const int row = threadIdx.x;
    float lse2;
    if (FAST) {
      float s = 0.f;
#pragma unroll
      for (int p = 0; p < 8; p++) s += ls[row][p];
      lse2 = mbArr[row] + lg2(s);          // exact: telescopes over the bias
    } else {
      float m = lm[row][0], s = ls[row][0];
#pragma unroll
      for (int p = 1; p < 8; p++) {
        const float mo = lm[row][p], so = ls[row][p];
        const float mn = fmaxf(m, mo);
        s = s * ex2(m - mn) + so * ex2(mo - mn);
        m = mn;
      }
      lse2 = m + lg2(s);
    }
    mbArr[row] = lse2;                     // next same-phase iteration's bias
    const float lse = lse2 * LN2F;         // natural-log LSE
    const int gi = b * NN + i0 + row;
    const float nu = cst + sav - EPSF * lse;
    coh_store(&wself2[gi], (nu - sav) * C10L2E);
    if (REC) {
      float du = fabsf(nu - uold);
#pragma unroll
      for (int off = 1; off < 64; off <<= 1) du += __shfl_xor(du, off, 64);
      if (threadIdx.x == 0) atomicAdd(errSlot, du);   // device-scope, no reader in loop
      uold = nu;
    }
  }
  __syncthreads();
}

// Persistent kernel: full Sinkhorn loop, one dispatch. 256 WGs x 512 thr
// (1 block/CU, 8 waves/CU -- R4 showed the 8-vs-16-wave axis is neutral here).
// b = blk&7 pins each batch to one XCD; barriers are per-batch (BPB=32 blocks).
// PASS1: run all MAX_ITER iterations, record err(t,b). PASS2 (rerun for exact
// freeze semantics): run *nIterDev iterations (0 => immediate exit, the case
// for non-early-converging inputs); replay is bit-deterministic.
template <bool PASS1>
__global__ __launch_bounds__(512, 2) void solve_kernel(
    const unsigned short* __restrict__ xh, const unsigned short* __restrict__ xl,
    const unsigned short* __restrict__ yh, const unsigned short* __restrict__ yl,
    const float* __restrict__ sx, const float* __restrict__ sy,
    float* __restrict__ wu2, float* __restrict__ wv2,
    float* __restrict__ errTab, int* __restrict__ gcnt,
    const int* __restrict__ nIterDev,
    float emu, float enu) {
  __shared__ float lm[64][8];
  __shared__ float ls[64][8];
  __shared__ float wlds[NN];
  __shared__ float mbu[64];
  __shared__ float mbv[64];
  const int b  = blockIdx.x & 7;
  const int i0 = (blockIdx.x >> 3) * 64;
  const int nIter = PASS1 ? MAX_ITER : *nIterDev;
  if (nIter == 0) return;   // pass 2 no-op when pass 1 state is already final

  // per-row constants & previous-u held in registers of the 64 writer threads
  float savx = 0.f, savy = 0.f, uold = 0.f, dummy = 0.f;
  if (threadIdx.x < 64) {
    savx = sx[b * NN + i0 + threadIdx.x];
    savy = sy[b * NN + i0 + threadIdx.x];
  }

  int* cnt = &gcnt[b * 32];
  int tgt = (PASS1 ? 0 : 2 * MAX_ITER) * BPB;

  for (int it = 0; it < nIter; ++it) {
    // u-phase: x rows vs all y, weights wv2 -> writes wu2 (+ err in pass 1)
    if (it < SAFE_ITERS)
      sweep_phase<PASS1, false>(xh, xl, yh, yl, wu2, wv2,
                                PASS1 ? &errTab[it * BB + b] : wu2,
                                b, i0, emu, savx, uold, lm, ls, wlds, mbu);
    else
      sweep_phase<PASS1, true>(xh, xl, yh, yl, wu2, wv2,
                               PASS1 ? &errTab[it * BB + b] : wu2,
                               b, i0, emu, savx, uold, lm, ls, wlds, mbu);
    tgt += BPB;
    batch_barrier(cnt, tgt);
    // v-phase: y rows vs all x (x panels carry the C20L2E scale) -> writes wv2
    if (it < SAFE_ITERS)
      sweep_phase<false, false>(yh, yl, xh, xl, wv2, wu2, wu2,
                                b, i0, enu, savy, dummy, lm, ls, wlds, mbv);
    else
      sweep_phase<false, true>(yh, yl, xh, xl, wv2, wu2, wu2,
                               b, i0, enu, savy, dummy, lm, ls, wlds, mbv);
    tgt += BPB;
    batch_barrier(cnt, tgt);
  }
}

// Find T* = first iteration with mean-batch err < THRESH. If T* < MAX_ITER-1,
// the reference would have frozen at state(T*): reset duals and request a
// rerun of T*+1 iterations (never taken for inputs that don't converge early).
__global__ __launch_bounds__(256) void tstar_kernel(const float* __restrict__ errTab,
                                                    int* __restrict__ nIterDev,
                                                    const float* __restrict__ sx,
                                                    const float* __restrict__ sy,
                                                    float* __restrict__ wu2,
                                                    float* __restrict__ wv2) {
  __shared__ int best;
  if (threadIdx.x == 0) best = MAX_ITER;
  __syncthreads();
  if (threadIdx.x < MAX_ITER) {
    float e = 0.f;
#pragma unroll
    for (int bb = 0; bb < BB; bb++) e += errTab[threadIdx.x * BB + bb];
    if (e * 0.125f < THRESHF) atomicMin(&best, (int)threadIdx.x);
  }
  __syncthreads();
  const int T = best;
  const int n2 = (T < MAX_ITER - 1) ? T + 1 : 0;
  if (threadIdx.x == 0) *nIterDev = n2;
  if (n2 > 0) {   // reset duals to iteration-0 state for the rerun
    for (int idx = threadIdx.x; idx < BB * NN; idx += 256) {
      wu2[idx] = -sx[idx] * C10L2E;
      wv2[idx] = -sy[idx] * C10L2E;
    }
  }
}

// S' = C20L2E*S (x panels pre-scaled). C = sx+sy-2S = fmaf(M2INV,S',sx+sy);
// pi = exp2(S' + wu2 + wv2); cost[b] += pi*C.
__global__ __launch_bounds__(256) void finalize_kernel(const unsigned short* __restrict__ xh,
                                                       const unsigned short* __restrict__ xl,
                                                       const unsigned short* __restrict__ yh,
                                                       const unsigned short* __restrict__ yl,
                                                       const float* __restrict__ sx,
                                                       const float* __restrict__ sy,
                                                       const float* __restrict__ wu2,
                                                       const float* __restrict__ wv2,
                                                       float* __restrict__ C,
                                                       float* __restrict__ pi,
                                                       float* __restrict__ cost) {
  const int b  = blockIdx.z;
  const int wv = threadIdx.x >> 6;
  const int lane = threadIdx.x & 63;
  const int l15 = lane & 15, q = lane >> 4;
  const int i0 = blockIdx.y * 128 + wv * 32;
  const int j0 = blockIdx.x * 256;

  const size_t arow0 = ((size_t)(b * NN + i0 + l15)) * DIM + q * 8;
  const sh8 a0h = *(const sh8*)(xh + arow0);
  const sh8 a0l = *(const sh8*)(xl + arow0);
  const sh8 a1h = *(const sh8*)(xh + arow0 + 16 * DIM);
  const sh8 a1l = *(const sh8*)(xl + arow0 + 16 * DIM);

  float sx0[8], wu0[8];
#pragma unroll
  for (int r = 0; r < 8; r++) {
    const int gi = b * NN + i0 + ((r < 4) ? (q * 4 + (r & 3)) : (16 + q * 4 + (r & 3)));
    sx0[r] = sx[gi];
    wu0[r] = wu2[gi];
  }

  float acc = 0.f;
#pragma unroll 2
  for (int tj = 0; tj < 16; tj++) {
    const int j = j0 + tj * 16;
    const size_t brow = ((size_t)(b * NN + j + l15)) * DIM + q * 8;
    const sh8 bh = *(const sh8*)(yh + brow);
    const sh8 bl = *(const sh8*)(yl + brow);
    f32x4 acc0 = {0.f, 0.f, 0.f, 0.f};
    f32x4 acc1 = {0.f, 0.f, 0.f, 0.f};
    acc0 = __builtin_amdgcn_mfma_f32_16x16x32_bf16(a0h, bh, acc0, 0, 0, 0);
    acc1 = __builtin_amdgcn_mfma_f32_16x16x32_bf16(a1h, bh, acc1, 0, 0, 0);
    acc0 = __builtin_amdgcn_mfma_f32_16x16x32_bf16(a0h, bl, acc0, 0, 0, 0);
    acc1 = __builtin_amdgcn_mfma_f32_16x16x32_bf16(a1h, bl, acc1, 0, 0, 0);
    acc0 = __builtin_amdgcn_mfma_f32_16x16x32_bf16(a0l, bh, acc0, 0, 0, 0);
    acc1 = __builtin_amdgcn_mfma_f32_16x16x32_bf16(a1l, bh, acc1, 0, 0, 0);
    const int gj = b * NN + j + l15;
    const float syj = sy[gj];
    const float wvj = wv2[gj];
#pragma unroll
    for (int r = 0; r < 8; r++) {
      const float Sp = (r < 4) ? acc0[r & 3] : acc1[r & 3];   // = C20L2E * S
      const int irow = i0 + ((r < 4) ? (q * 4 + (r & 3)) : (16 + q * 4 + (r & 3)));
      const float Cv = fmaf(M2INV, Sp, sx0[r] + syj);
      const float p  = ex2(Sp + (wu0[r] + wvj));
      const size_t addr = ((size_t)(b * NN + irow)) * NN + j + l15;
      C[addr]  = Cv;
      pi[addr] = p;
      acc = fmaf(p, Cv, acc);
    }
  }
#pragma unroll
  for (int off = 1; off < 64; off <<= 1) acc += __shfl_xor(acc, off, 64);
  __shared__ float red[4];
  if (lane == 0) red[wv] = acc;
  __syncthreads();
  if (threadIdx.x == 0) atomicAdd(&cost[b], red[0] + red[1] + red[2] + red[3]);
}

extern "C" void kernel_launch(void* const* d_in, const int* in_sizes, int n_in,
                              void* d_out, int out_size, void* d_ws, size_t ws_size,
                              hipStream_t stream) {
  const float* x = (const float*)d_in[0];
  const float* y = (const float*)d_in[1];
  float* out  = (float*)d_out;
  float* cost = out;                              // [8]
  float* pi   = out + 8;                          // [8,2048,2048]
  float* C    = out + 8 + (size_t)BB * NN * NN;   // [8,2048,2048]

  float* ws = (float*)d_ws;
  const int BN = BB * NN;                         // 16384
  float* wu2 = ws;                                // [16384]
  float* wv2 = ws + BN;
  float* sx  = ws + 2 * BN;
  float* sy  = ws + 3 * BN;
  float* errTab = ws + 4 * BN;                    // [100*8], zeroed
  int*   gcnt   = (int*)(ws + 4 * BN + 1024);     // 8 counters, stride 32 ints
  int*   nIterDev = (int*)(ws + 4 * BN + 1280);
  unsigned short* xh = (unsigned short*)(ws + 4 * BN + 1536);
  const size_t NE = (size_t)BB * NN * DIM;        // 524288
  unsigned short* xl = xh + NE;
  unsigned short* yh = xh + 2 * NE;
  unsigned short* yl = xh + 3 * NE;

  // zero errTab + barrier counters + nIter (prep rewrites wu2/wv2/sx/sy)
  hipMemsetAsync(errTab, 0, 1536 * sizeof(float), stream);
  hipMemsetAsync(d_out, 0, 8 * sizeof(float), stream);

  prep_kernel<<<2048, 256, 0, stream>>>(x, xh, xl, sx, wu2, C20L2E);  // x scaled
  prep_kernel<<<2048, 256, 0, stream>>>(y, yh, yl, sy, wv2, 1.0f);    // y unscaled

  const float emu = (float)(0.1 * log(1.0 / 2048.0 + 1e-8));
  const float enu = emu;

  solve_kernel<true><<<256, 512, 0, stream>>>(xh, xl, yh, yl, sx, sy, wu2, wv2,
                                              errTab, gcnt, nIterDev, emu, enu);
  tstar_kernel<<<1, 256, 0, stream>>>(errTab, nIterDev, sx, sy, wu2, wv2);
  solve_kernel<false><<<256, 512, 0, stream>>>(xh, xl, yh, yl, sx, sy, wu2, wv2,
                                               errTab, gcnt, nIterDev, emu, enu);

  finalize_kernel<<<dim3(8, 16, BB), 256, 0, stream>>>(xh, xl, yh, yl, sx, sy,
                                                       wu2, wv2, C, pi, cost);
}